// Round 5
// baseline (1154.159 us; speedup 1.0000x reference)
//
#include <hip/hip_runtime.h>
#include <math.h>

// ---------------------------------------------------------------------------
// Hyena forward, MI355X.  B=2, L=8192, C=1024, ORDER=2.
// R3 (resubmitted R4 after infra timeout): conv_fft -> register-blocked FFT.
// 1024 threads x 16 float2 regs; phases A(q=4096,1024) B(256,64) C(16,4) D(1)
// each do TWO radix-4 stages in regs per LDS round-trip. Phase D fuses
// fwd-q1 + spectral-mul + inv-q1 (no twiddles); H spectrum lives entirely in
// registers. Global-direct input (phase A) and output (phase A').
// Sincos/FFT 28->15, LDS passes ~48->18, syncs 21->10.
// GEMM path unchanged from R1/R2 (split-bf16 MFMA, 3-product).
// ---------------------------------------------------------------------------

constexpr int Lseq = 8192;
constexpr int Cd   = 1024;
constexpr int BL   = 16384;   // B * L
constexpr int NF   = 16384;   // FFT length = 2L
constexpr int KK   = 1024;    // GEMM K dim (both GEMMs)

// ws layout (float offsets)
constexpr size_t BIG_OFF  = 0;                                  // [2048][BL] fp32: rows 0-1023 v, 1024-2047 gate->y
constexpr size_t COEF_OFF = BIG_OFF + (size_t)2048 * BL;
constexpr size_t W2TH_OFF = COEF_OFF + (size_t)Cd * Lseq;
constexpr size_t W2TL_OFF = W2TH_OFF + (size_t)2048 * 1024 / 2;
constexpr size_t WOTH_OFF = W2TL_OFF + (size_t)2048 * 1024 / 2;
constexpr size_t WOTL_OFF = WOTH_OFF + (size_t)1024 * 1024 / 2;
constexpr size_t B2_OFF   = WOTL_OFF + (size_t)1024 * 1024 / 2;
constexpr size_t WS_FLOATS = B2_OFF + 2048;                     // 180,363,264 B

using bf16x8 = __attribute__((ext_vector_type(8))) short;
using f32x4  = __attribute__((ext_vector_type(4))) float;

__device__ inline unsigned short f2bf(float f) {
  unsigned u = __float_as_uint(f);
  u += 0x7FFFu + ((u >> 16) & 1u);
  return (unsigned short)(u >> 16);
}
__device__ inline float bf2f(unsigned short h) { return __uint_as_float(((unsigned)h) << 16); }

__device__ inline void gload_lds16(const void* g, void* l) {
  __builtin_amdgcn_global_load_lds((const __attribute__((address_space(1))) unsigned int*)g,
                                   (__attribute__((address_space(3))) unsigned int*)l, 16, 0, 0);
}

// ---------------------------------------------------------------------------
// complex helpers
__device__ inline float2 cadd(float2 a, float2 b){ return make_float2(a.x+b.x, a.y+b.y); }
__device__ inline float2 csub(float2 a, float2 b){ return make_float2(a.x-b.x, a.y-b.y); }
__device__ inline float2 cmul(float2 a, float2 b){ return make_float2(a.x*b.x - a.y*b.y, a.x*b.y + a.y*b.x); }
__device__ inline float2 cmulc(float2 a, float2 w){ return make_float2(a.x*w.x + a.y*w.y, a.y*w.x - a.x*w.y); }

// padded LDS index: 1 float2 pad per 16 -> all phase access patterns land on
// the free 4-way minimum for wave64 ds_read_b64.
__device__ inline int PD(int i) { return i + (i >> 4); }

// W_N^m = e^{-2*pi*i*m/16384}; w2 = w1^2, w3 = w1*w2.
__device__ inline void tw3(int m1, float2& w1, float2& w2, float2& w3) {
  float s, c;
  __sincosf((float)m1 * -3.8349519697141029e-4f, &s, &c);   // -2*pi/16384
  w1 = make_float2(c, s);
  w2 = make_float2(c*c - s*s, 2.f*c*s);
  w3 = cmul(w1, w2);
}

// DIF radix-4 butterfly, output twiddles
__device__ inline void bfly4_fwd(float2& A, float2& B, float2& C, float2& D,
                                 float2 w1, float2 w2, float2 w3) {
  float2 t0 = cadd(A, C), t1 = csub(A, C);
  float2 t2 = cadd(B, D), t3 = csub(B, D);
  float2 y0 = cadd(t0, t2), y2 = csub(t0, t2);
  float2 y1 = make_float2(t1.x + t3.y, t1.y - t3.x);   // t1 - i*t3
  float2 y3 = make_float2(t1.x - t3.y, t1.y + t3.x);   // t1 + i*t3
  A = y0; B = cmul(y1, w1); C = cmul(y2, w2); D = cmul(y3, w3);
}
__device__ inline void bfly4_fwd_nt(float2& A, float2& B, float2& C, float2& D) {
  float2 t0 = cadd(A, C), t1 = csub(A, C);
  float2 t2 = cadd(B, D), t3 = csub(B, D);
  float2 y1 = make_float2(t1.x + t3.y, t1.y - t3.x);
  float2 y3 = make_float2(t1.x - t3.y, t1.y + t3.x);
  A = cadd(t0, t2); C = csub(t0, t2); B = y1; D = y3;
}
// DIT radix-4 butterfly, input twiddles (conjugated)
__device__ inline void bfly4_inv(float2& A, float2& B, float2& C, float2& D,
                                 float2 w1, float2 w2, float2 w3) {
  float2 b = cmulc(B, w1), c = cmulc(C, w2), e = cmulc(D, w3);
  float2 s0 = cadd(A, c), s1 = csub(A, c);
  float2 s2 = cadd(b, e), s3 = csub(b, e);
  A = cadd(s0, s2); C = csub(s0, s2);
  B = make_float2(s1.x - s3.y, s1.y + s3.x);   // s1 + i*s3
  D = make_float2(s1.x + s3.y, s1.y - s3.x);   // s1 - i*s3
}
__device__ inline void bfly4_inv_nt(float2& A, float2& B, float2& C, float2& D) {
  float2 s0 = cadd(A, C), s1 = csub(A, C);
  float2 s2 = cadd(B, D), s3 = csub(B, D);
  A = cadd(s0, s2); C = csub(s0, s2);
  B = make_float2(s1.x - s3.y, s1.y + s3.x);
  D = make_float2(s1.x + s3.y, s1.y - s3.x);
}

// ---- phase butterflies (two stages each, all reg indices compile-time) ----
// A: elements {t + 1024j}; stages q=4096 (m1 = t+1024*j0), q=1024 (m1 = 4t)
__device__ inline void phaseA_fwd(float2 (&d)[16], int t) {
  float2 w1, w2, w3;
  #pragma unroll
  for (int j0 = 0; j0 < 4; ++j0) {
    tw3(t + 1024*j0, w1, w2, w3);
    bfly4_fwd(d[j0], d[j0+4], d[j0+8], d[j0+12], w1, w2, w3);
  }
  tw3(4*t, w1, w2, w3);
  #pragma unroll
  for (int a = 0; a < 4; ++a)
    bfly4_fwd(d[4*a], d[4*a+1], d[4*a+2], d[4*a+3], w1, w2, w3);
}
__device__ inline void phaseA_inv(float2 (&d)[16], int t) {
  float2 w1, w2, w3;
  tw3(4*t, w1, w2, w3);
  #pragma unroll
  for (int a = 0; a < 4; ++a)
    bfly4_inv(d[4*a], d[4*a+1], d[4*a+2], d[4*a+3], w1, w2, w3);
  #pragma unroll
  for (int j0 = 0; j0 < 4; ++j0) {
    tw3(t + 1024*j0, w1, w2, w3);
    bfly4_inv(d[j0], d[j0+4], d[j0+8], d[j0+12], w1, w2, w3);
  }
}
// B: elements {g*1024 + r + 64j}; stages q=256 (m1=(r+64j0)<<4), q=64 (m1=r<<6)
__device__ inline void phaseB_fwd(float2 (&d)[16], int r) {
  float2 w1, w2, w3;
  #pragma unroll
  for (int j0 = 0; j0 < 4; ++j0) {
    tw3((r + 64*j0) << 4, w1, w2, w3);
    bfly4_fwd(d[j0], d[j0+4], d[j0+8], d[j0+12], w1, w2, w3);
  }
  tw3(r << 6, w1, w2, w3);
  #pragma unroll
  for (int a = 0; a < 4; ++a)
    bfly4_fwd(d[4*a], d[4*a+1], d[4*a+2], d[4*a+3], w1, w2, w3);
}
__device__ inline void phaseB_inv(float2 (&d)[16], int r) {
  float2 w1, w2, w3;
  tw3(r << 6, w1, w2, w3);
  #pragma unroll
  for (int a = 0; a < 4; ++a)
    bfly4_inv(d[4*a], d[4*a+1], d[4*a+2], d[4*a+3], w1, w2, w3);
  #pragma unroll
  for (int j0 = 0; j0 < 4; ++j0) {
    tw3((r + 64*j0) << 4, w1, w2, w3);
    bfly4_inv(d[j0], d[j0+4], d[j0+8], d[j0+12], w1, w2, w3);
  }
}
// C: elements {run*64 + u + 4j}; stages q=16 (m1=(u+4j0)<<8), q=4 (m1=u<<10)
__device__ inline void phaseC_fwd(float2 (&d)[16], int u) {
  float2 w1, w2, w3;
  #pragma unroll
  for (int j0 = 0; j0 < 4; ++j0) {
    tw3((u + 4*j0) << 8, w1, w2, w3);
    bfly4_fwd(d[j0], d[j0+4], d[j0+8], d[j0+12], w1, w2, w3);
  }
  tw3(u << 10, w1, w2, w3);
  #pragma unroll
  for (int a = 0; a < 4; ++a)
    bfly4_fwd(d[4*a], d[4*a+1], d[4*a+2], d[4*a+3], w1, w2, w3);
}
__device__ inline void phaseC_inv(float2 (&d)[16], int u) {
  float2 w1, w2, w3;
  tw3(u << 10, w1, w2, w3);
  #pragma unroll
  for (int a = 0; a < 4; ++a)
    bfly4_inv(d[4*a], d[4*a+1], d[4*a+2], d[4*a+3], w1, w2, w3);
  #pragma unroll
  for (int j0 = 0; j0 < 4; ++j0) {
    tw3((u + 4*j0) << 8, w1, w2, w3);
    bfly4_inv(d[j0], d[j0+4], d[j0+8], d[j0+12], w1, w2, w3);
  }
}

// ---------------------------------------------------------------------------
// 1) filter MLP trunk -> h2 [8192][128] (aliases W2T region; runs first)
__global__ __launch_bounds__(256) void mlp_kernel(const float* __restrict__ fw1, const float* __restrict__ fb1,
                                                  const float* __restrict__ fw2, const float* __restrict__ fb2,
                                                  float* __restrict__ h2) {
  __shared__ float sw2[64 * 128];
  __shared__ float sw1[64], sb1[64], sb2[128];
  int t = threadIdx.x;
  for (int i = t; i < 64 * 128; i += 256) sw2[i] = fw2[i];
  if (t < 64)  { sw1[t] = fw1[t]; sb1[t] = fb1[t]; }
  if (t < 128) sb2[t] = fb2[t];
  __syncthreads();
  int l = blockIdx.x * 256 + t;
  float pos = (float)l / 8191.0f;
  float h1[64];
  #pragma unroll
  for (int j = 0; j < 64; ++j) {
    float xx = pos * sw1[j] + sb1[j];
    h1[j] = 0.5f * xx * (1.0f + erff(xx * 0.7071067811865475f));
  }
  for (int m = 0; m < 128; ++m) {
    float acc = sb2[m];
    #pragma unroll
    for (int j = 0; j < 64; ++j) acc += h1[j] * sw2[j * 128 + m];
    h2[(size_t)l * 128 + m] = 0.5f * acc * (1.0f + erff(acc * 0.7071067811865475f));
  }
}

// ---------------------------------------------------------------------------
// 2) coef GEMM (fp32): h2(8192x128) @ fw3[:,2c+1] + fb3[2c+1] -> coefs_t[c][l]
__global__ __launch_bounds__(256) void gemm_coefs_kernel(const float* __restrict__ H2,
    const float* __restrict__ FW3, const float* __restrict__ FB3,
    float* __restrict__ coefs) {
  __shared__ float As[16 * 72];
  __shared__ float Bs[16 * 72];
  int t  = threadIdx.x;
  int n0 = blockIdx.x * 64;   // channel tile
  int m0 = blockIdx.y * 64;   // l tile
  int tr = t >> 4, tc = t & 15;
  float acc[4][4] = {};
  int am = t >> 2, ak = (t & 3) * 4;
  int bk = t >> 4, bn = (t & 15) * 4;
  for (int k0 = 0; k0 < 128; k0 += 16) {
    float4 a = *(const float4*)&H2[(size_t)(m0 + am) * 128 + k0 + ak];
    float b0 = FW3[(size_t)(k0 + bk) * 2048 + 2 * (n0 + bn + 0) + 1];
    float b1 = FW3[(size_t)(k0 + bk) * 2048 + 2 * (n0 + bn + 1) + 1];
    float b2 = FW3[(size_t)(k0 + bk) * 2048 + 2 * (n0 + bn + 2) + 1];
    float b3 = FW3[(size_t)(k0 + bk) * 2048 + 2 * (n0 + bn + 3) + 1];
    __syncthreads();
    As[(ak + 0) * 72 + am] = a.x;
    As[(ak + 1) * 72 + am] = a.y;
    As[(ak + 2) * 72 + am] = a.z;
    As[(ak + 3) * 72 + am] = a.w;
    Bs[bk * 72 + bn + 0] = b0;
    Bs[bk * 72 + bn + 1] = b1;
    Bs[bk * 72 + bn + 2] = b2;
    Bs[bk * 72 + bn + 3] = b3;
    __syncthreads();
    #pragma unroll
    for (int kk = 0; kk < 16; ++kk) {
      float4 av = *(const float4*)&As[kk * 72 + tr * 4];
      float4 bv = *(const float4*)&Bs[kk * 72 + tc * 4];
      float aa[4] = {av.x, av.y, av.z, av.w};
      float bb[4] = {bv.x, bv.y, bv.z, bv.w};
      #pragma unroll
      for (int i = 0; i < 4; ++i)
        #pragma unroll
        for (int j = 0; j < 4; ++j)
          acc[i][j] += aa[i] * bb[j];
    }
  }
  #pragma unroll
  for (int j = 0; j < 4; ++j) {
    int c = n0 + tc * 4 + j;
    float bias = FB3[2 * c + 1];
    float4 val = make_float4(acc[0][j] + bias, acc[1][j] + bias, acc[2][j] + bias, acc[3][j] + bias);
    *(float4*)&coefs[(size_t)c * Lseq + m0 + tr * 4] = val;
  }
}

// ---------------------------------------------------------------------------
// 3) compact+transpose+split in_proj weights
__global__ __launch_bounds__(256) void compact_w_kernel(const float* __restrict__ w, const float* __restrict__ b,
    unsigned short* __restrict__ w2h, unsigned short* __restrict__ w2l, float* __restrict__ b2) {
  __shared__ float t[64 * 65];
  int n0 = blockIdx.x * 64;
  int k0 = blockIdx.y * 64;
  int tid = threadIdx.x;
  #pragma unroll
  for (int i = 0; i < 16; ++i) {
    int idx = tid + i * 256;
    int nr = idx & 63, kr = idx >> 6;
    int n = n0 + nr;
    int src = (n < 1024) ? 3 * n : 3 * (n - 1024) + 2;
    t[nr * 65 + kr] = w[(size_t)(k0 + kr) * 3072 + src];
  }
  __syncthreads();
  #pragma unroll
  for (int i = 0; i < 16; ++i) {
    int idx = tid + i * 256;
    int kr = idx & 63, nr = idx >> 6;
    float v = t[nr * 65 + kr];
    unsigned short h = f2bf(v);
    size_t o = (size_t)(n0 + nr) * 1024 + k0 + kr;
    w2h[o] = h;
    w2l[o] = f2bf(v - bf2f(h));
  }
  if (blockIdx.y == 0 && tid < 64) {
    int n = n0 + tid;
    int src = (n < 1024) ? 3 * n : 3 * (n - 1024) + 2;
    b2[n] = b[src];
  }
}

// ---------------------------------------------------------------------------
// 4) transpose+split out_w -> WoT hi/lo bf16 [n][k]
__global__ __launch_bounds__(256) void wout_t_kernel(const float* __restrict__ w,
    unsigned short* __restrict__ wh, unsigned short* __restrict__ wl) {
  __shared__ float t[64 * 65];
  int n0 = blockIdx.x * 64, k0 = blockIdx.y * 64;
  int tid = threadIdx.x;
  #pragma unroll
  for (int i = 0; i < 16; ++i) {
    int idx = tid + i * 256;
    int nr = idx & 63, kr = idx >> 6;
    t[nr * 65 + kr] = w[(size_t)(k0 + kr) * 1024 + n0 + nr];
  }
  __syncthreads();
  #pragma unroll
  for (int i = 0; i < 16; ++i) {
    int idx = tid + i * 256;
    int kr = idx & 63, nr = idx >> 6;
    float v = t[nr * 65 + kr];
    unsigned short h = f2bf(v);
    size_t o = (size_t)(n0 + nr) * 1024 + k0 + kr;
    wh[o] = h;
    wl[o] = f2bf(v - bf2f(h));
  }
}

// ---------------------------------------------------------------------------
// 5) split x fp32 -> Xhi/Xlo bf16, into d_out scratch
__global__ __launch_bounds__(256) void convert_x_kernel(const float* __restrict__ x,
    unsigned short* __restrict__ xhi, unsigned short* __restrict__ xlo) {
  size_t i = (size_t)blockIdx.x * 256 + threadIdx.x;
  size_t stride = (size_t)gridDim.x * 256;
  size_t n4 = (size_t)BL * 1024 / 4;
  for (; i < n4; i += stride) {
    float4 v = *(const float4*)&x[i * 4];
    ushort4 h, l;
    h.x = f2bf(v.x); l.x = f2bf(v.x - bf2f(h.x));
    h.y = f2bf(v.y); l.y = f2bf(v.y - bf2f(h.y));
    h.z = f2bf(v.z); l.z = f2bf(v.z - bf2f(h.z));
    h.w = f2bf(v.w); l.w = f2bf(v.w - bf2f(h.w));
    *(ushort4*)&xhi[i * 4] = h;
    *(ushort4*)&xlo[i * 4] = l;
  }
}

// ---------------------------------------------------------------------------
// 6) transpose+split y fp32 [1024 c][BL m] -> Yhi/Ylo bf16 [m][c]
__global__ __launch_bounds__(256) void transpose_y_kernel(const float* __restrict__ y,
    unsigned short* __restrict__ yh, unsigned short* __restrict__ yl) {
  __shared__ float t[64 * 65];
  int m0 = blockIdx.x * 64, c0 = blockIdx.y * 64;
  int tid = threadIdx.x;
  #pragma unroll
  for (int i = 0; i < 16; ++i) {
    int idx = tid + i * 256;
    int mr = idx & 63, cr = idx >> 6;
    t[cr * 65 + mr] = y[(size_t)(c0 + cr) * BL + m0 + mr];
  }
  __syncthreads();
  #pragma unroll
  for (int i = 0; i < 16; ++i) {
    int idx = tid + i * 256;
    int cr = idx & 63, mr = idx >> 6;
    float v = t[cr * 65 + mr];
    unsigned short h = f2bf(v);
    size_t o = (size_t)(m0 + mr) * 1024 + c0 + cr;
    yh[o] = h;
    yl[o] = f2bf(v - bf2f(h));
  }
}

// ---------------------------------------------------------------------------
// 7) split-bf16 MFMA GEMM (unchanged from R1)
template<int BIAS_MODE>
__global__ __launch_bounds__(256) void gemm_bt_mfma(
    const unsigned short* __restrict__ Ahi, const unsigned short* __restrict__ Alo,
    const unsigned short* __restrict__ Bhi, const unsigned short* __restrict__ Blo,
    float* __restrict__ Cc, size_t ldc, const float* __restrict__ bias) {
  __shared__ unsigned short lds[4][128 * 32];
  int tid  = threadIdx.x;
  int lane = tid & 63;
  int wid  = tid >> 6;
  int wr = wid >> 1, wc = wid & 1;
  size_t row0 = (size_t)blockIdx.y * 128;
  size_t col0 = (size_t)blockIdx.x * 128;

  f32x4 acc[4][4];
  #pragma unroll
  for (int i = 0; i < 4; ++i)
    #pragma unroll
    for (int j = 0; j < 4; ++j) acc[i][j] = (f32x4){0.f, 0.f, 0.f, 0.f};

  const unsigned short* srcs[4] = {Ahi + row0 * KK, Alo + row0 * KK,
                                   Bhi + col0 * KK, Blo + col0 * KK};
  int ko = (lane >> 4) * 8;

  for (int k0 = 0; k0 < KK; k0 += 32) {
    #pragma unroll
    for (int t4 = 0; t4 < 4; ++t4) {
      const unsigned short* sp = srcs[t4] + k0;
      #pragma unroll
      for (int h = 0; h < 2; ++h) {
        int q = h * 256 + tid;
        int r = q >> 2, kp = (q & 3) * 8;
        gload_lds16(sp + (size_t)r * KK + kp, &lds[t4][q * 8]);
      }
    }
    __syncthreads();
    bf16x8 ah[4], al[4], bh[4], bl[4];
    #pragma unroll
    for (int f = 0; f < 4; ++f) {
      int ra = wr * 64 + f * 16 + (lane & 15);
      int rb = wc * 64 + f * 16 + (lane & 15);
      ah[f] = *(const bf16x8*)&lds[0][ra * 32 + ko];
      al[f] = *(const bf16x8*)&lds[1][ra * 32 + ko];
      bh[f] = *(const bf16x8*)&lds[2][rb * 32 + ko];
      bl[f] = *(const bf16x8*)&lds[3][rb * 32 + ko];
    }
    #pragma unroll
    for (int i = 0; i < 4; ++i)
      #pragma unroll
      for (int j = 0; j < 4; ++j) {
        acc[i][j] = __builtin_amdgcn_mfma_f32_16x16x32_bf16(ah[i], bh[j], acc[i][j], 0, 0, 0);
        acc[i][j] = __builtin_amdgcn_mfma_f32_16x16x32_bf16(ah[i], bl[j], acc[i][j], 0, 0, 0);
        acc[i][j] = __builtin_amdgcn_mfma_f32_16x16x32_bf16(al[i], bh[j], acc[i][j], 0, 0, 0);
      }
    __syncthreads();
  }

  #pragma unroll
  for (int i = 0; i < 4; ++i) {
    #pragma unroll
    for (int rr = 0; rr < 4; ++rr) {
      size_t row = row0 + wr * 64 + i * 16 + (lane >> 4) * 4 + rr;
      float rb = (BIAS_MODE == 0) ? bias[row] : 0.f;
      #pragma unroll
      for (int j = 0; j < 4; ++j) {
        size_t col = col0 + wc * 64 + j * 16 + (lane & 15);
        float cb = (BIAS_MODE == 1) ? bias[col] : rb;
        Cc[row * ldc + col] = acc[i][j][rr] + cb;
      }
    }
  }
}

// ---------------------------------------------------------------------------
// 8) per-channel FFT conv: register-blocked phases, fused spectral multiply.
__global__ __launch_bounds__(1024, 4) void conv_fft_kernel(
    const float* __restrict__ vt, float* __restrict__ x2t,
    const float* __restrict__ coefs,
    const float* __restrict__ short_w, const float* __restrict__ short_b) {
  extern __shared__ float2 z[];      // PD-padded: 17408 float2 = 139,264 B
  int t = threadIdx.x;
  int c = blockIdx.x;
  int rB = t & 63;
  int baseB = (t >> 6) * 1024 + rB;  // phase-B element base
  int u = t & 3;
  int baseC = (t >> 2) * 64 + u;     // phase-C element base

  float2 d[16];
  float2 Hreg[16];
  constexpr float invN = 1.0f / (float)NF;

  // ================= H pipeline: coefs -> spectrum in Hreg =================
  {
    const float* cf = coefs + (size_t)c * Lseq;
    #pragma unroll
    for (int j = 0; j < 8; ++j)  d[j] = make_float2(cf[t + 1024 * j], 0.f);
    #pragma unroll
    for (int j = 8; j < 16; ++j) d[j] = make_float2(0.f, 0.f);
    phaseA_fwd(d, t);
    #pragma unroll
    for (int j = 0; j < 16; ++j) z[PD(t + 1024 * j)] = d[j];
    __syncthreads();

    #pragma unroll
    for (int j = 0; j < 16; ++j) d[j] = z[PD(baseB + 64 * j)];
    phaseB_fwd(d, rB);
    #pragma unroll
    for (int j = 0; j < 16; ++j) z[PD(baseB + 64 * j)] = d[j];
    __syncthreads();

    #pragma unroll
    for (int j = 0; j < 16; ++j) d[j] = z[PD(baseC + 4 * j)];
    phaseC_fwd(d, u);
    #pragma unroll
    for (int j = 0; j < 16; ++j) z[PD(baseC + 4 * j)] = d[j];
    __syncthreads();

    #pragma unroll
    for (int s = 0; s < 4; ++s) {
      int ib = 17 * t + 4 * s;           // PD(16t + 4s): contiguous quad
      float2 A = z[ib], B = z[ib + 1], C = z[ib + 2], D = z[ib + 3];
      bfly4_fwd_nt(A, B, C, D);
      Hreg[4*s+0] = make_float2(A.x * invN, A.y * invN);
      Hreg[4*s+1] = make_float2(B.x * invN, B.y * invN);
      Hreg[4*s+2] = make_float2(C.x * invN, C.y * invN);
      Hreg[4*s+3] = make_float2(D.x * invN, D.y * invN);
    }
    __syncthreads();
  }

  // ================= v pipeline: short conv -> FFT -> xH -> IFFT ==========
  {
    float sw0 = short_w[c * 3 + 0], sw1 = short_w[c * 3 + 1], sw2 = short_w[c * 3 + 2];
    float sbv = short_b[c];
    const float* v0 = vt + (size_t)c * BL;
    const float* v1 = v0 + Lseq;
    #pragma unroll
    for (int j = 0; j < 8; ++j) {
      int l = t + 1024 * j;
      float a0 = (l > 0)        ? v0[l - 1] : 0.f;
      float b0 = v0[l];
      float c0 = (l < Lseq - 1) ? v0[l + 1] : 0.f;
      float a1 = (l > 0)        ? v1[l - 1] : 0.f;
      float b1 = v1[l];
      float c1 = (l < Lseq - 1) ? v1[l + 1] : 0.f;
      d[j] = make_float2(sw0 * a0 + sw1 * b0 + sw2 * c0 + sbv,
                         sw0 * a1 + sw1 * b1 + sw2 * c1 + sbv);
    }
    #pragma unroll
    for (int j = 8; j < 16; ++j) d[j] = make_float2(0.f, 0.f);
    phaseA_fwd(d, t);
    #pragma unroll
    for (int j = 0; j < 16; ++j) z[PD(t + 1024 * j)] = d[j];
    __syncthreads();

    #pragma unroll
    for (int j = 0; j < 16; ++j) d[j] = z[PD(baseB + 64 * j)];
    phaseB_fwd(d, rB);
    #pragma unroll
    for (int j = 0; j < 16; ++j) z[PD(baseB + 64 * j)] = d[j];
    __syncthreads();

    #pragma unroll
    for (int j = 0; j < 16; ++j) d[j] = z[PD(baseC + 4 * j)];
    phaseC_fwd(d, u);
    #pragma unroll
    for (int j = 0; j < 16; ++j) z[PD(baseC + 4 * j)] = d[j];
    __syncthreads();

    // phase D: fwd q=1 (no twiddle) + spectral multiply + inv q=1 (no twiddle)
    #pragma unroll
    for (int s = 0; s < 4; ++s) {
      int ib = 17 * t + 4 * s;
      float2 A = z[ib], B = z[ib + 1], C = z[ib + 2], D = z[ib + 3];
      bfly4_fwd_nt(A, B, C, D);
      A = cmul(A, Hreg[4*s+0]); B = cmul(B, Hreg[4*s+1]);
      C = cmul(C, Hreg[4*s+2]); D = cmul(D, Hreg[4*s+3]);
      bfly4_inv_nt(A, B, C, D);
      z[ib] = A; z[ib + 1] = B; z[ib + 2] = C; z[ib + 3] = D;
    }
    __syncthreads();

    #pragma unroll
    for (int j = 0; j < 16; ++j) d[j] = z[PD(baseC + 4 * j)];
    phaseC_inv(d, u);
    #pragma unroll
    for (int j = 0; j < 16; ++j) z[PD(baseC + 4 * j)] = d[j];
    __syncthreads();

    #pragma unroll
    for (int j = 0; j < 16; ++j) d[j] = z[PD(baseB + 64 * j)];
    phaseB_inv(d, rB);
    #pragma unroll
    for (int j = 0; j < 16; ++j) z[PD(baseB + 64 * j)] = d[j];
    __syncthreads();

    #pragma unroll
    for (int j = 0; j < 16; ++j) d[j] = z[PD(t + 1024 * j)];
    phaseA_inv(d, t);

    // gate multiply + write (only first L outputs per batch are needed)
    float* y0 = x2t + (size_t)c * BL;
    float* y1 = y0 + Lseq;
    #pragma unroll
    for (int j = 0; j < 8; ++j) {
      int l = t + 1024 * j;
      y0[l] = y0[l] * d[j].x;
      y1[l] = y1[l] * d[j].y;
    }
  }
}

// ---------------------------------------------------------------------------
extern "C" void kernel_launch(void* const* d_in, const int* in_sizes, int n_in,
                              void* d_out, int out_size, void* d_ws, size_t ws_size,
                              hipStream_t stream) {
  (void)in_sizes; (void)n_in; (void)out_size;
  const float* x    = (const float*)d_in[0];
  const float* ipw  = (const float*)d_in[1];
  const float* ipb  = (const float*)d_in[2];
  const float* sw   = (const float*)d_in[3];
  const float* sb   = (const float*)d_in[4];
  const float* fw1  = (const float*)d_in[5];
  const float* fb1  = (const float*)d_in[6];
  const float* fw2  = (const float*)d_in[7];
  const float* fb2  = (const float*)d_in[8];
  const float* fw3  = (const float*)d_in[9];
  const float* fb3  = (const float*)d_in[10];
  const float* outw = (const float*)d_in[11];
  const float* outb = (const float*)d_in[12];
  float* out = (float*)d_out;
  float* ws  = (float*)d_ws;

  if (ws_size < WS_FLOATS * 4) return;

  float*          big   = ws + BIG_OFF;
  float*          vt    = big;
  float*          x2t   = big + (size_t)Cd * BL;
  float*          coefs = ws + COEF_OFF;
  unsigned short* w2h   = (unsigned short*)(ws + W2TH_OFF);
  unsigned short* w2l   = (unsigned short*)(ws + W2TL_OFF);
  unsigned short* woh   = (unsigned short*)(ws + WOTH_OFF);
  unsigned short* wol   = (unsigned short*)(ws + WOTL_OFF);
  float*          b2    = ws + B2_OFF;
  float*          h2    = ws + W2TH_OFF;                   // transient alias
  unsigned short* xhi   = (unsigned short*)d_out;
  unsigned short* xlo   = xhi + (size_t)BL * 1024;
  unsigned short* yhi   = (unsigned short*)big;
  unsigned short* ylo   = yhi + (size_t)BL * 1024;

  constexpr int CONV_LDS = 17408 * 8;   // 139,264 B
  hipFuncSetAttribute(reinterpret_cast<const void*>(conv_fft_kernel),
                      hipFuncAttributeMaxDynamicSharedMemorySize, CONV_LDS);

  mlp_kernel<<<32, 256, 0, stream>>>(fw1, fb1, fw2, fb2, h2);
  gemm_coefs_kernel<<<dim3(16, 128), 256, 0, stream>>>(h2, fw3, fb3, coefs);
  compact_w_kernel<<<dim3(32, 16), 256, 0, stream>>>(ipw, ipb, w2h, w2l, b2);
  wout_t_kernel<<<dim3(16, 16), 256, 0, stream>>>(outw, woh, wol);
  convert_x_kernel<<<2048, 256, 0, stream>>>(x, xhi, xlo);
  gemm_bt_mfma<0><<<dim3(128, 16), 256, 0, stream>>>(w2h, w2l, xhi, xlo, big, (size_t)BL, b2);
  conv_fft_kernel<<<1024, 1024, CONV_LDS, stream>>>(vt, x2t, coefs, sw, sb);
  transpose_y_kernel<<<dim3(256, 16), 256, 0, stream>>>(x2t, yhi, ylo);
  gemm_bt_mfma<1><<<dim3(8, 128), 256, 0, stream>>>(yhi, ylo, woh, wol, out, (size_t)1024, outb);
}